// Round 7
// baseline (648.319 us; speedup 1.0000x reference)
//
#include <hip/hip_runtime.h>

#define M_TOTAL   2000000
#define NT        512
#define K1_BLOCKS 1024
#define K3_BLOCKS 2048

__device__ __forceinline__ float rlf(float v, int l) {
    union { float f; int i; } u; u.f = v;
    u.i = __builtin_amdgcn_readlane(u.i, l);
    return u.f;
}

// Barrier with LDS-only drain: in-loop cross-thread data is exclusively LDS,
// so vmcnt (global outL stores / gum / Rtab loads) never needs draining.
__device__ __forceinline__ void bar_lds() {
    asm volatile("s_waitcnt lgkmcnt(0)" ::: "memory");
    __builtin_amdgcn_s_barrier();
    asm volatile("" ::: "memory");
}

// DPP helpers (register-crossbar cross-lane, ~4cy vs ~100cy for ds_bpermute shuffles).
#define DPPMAXU(m, ctrl) { unsigned _d = (unsigned)__builtin_amdgcn_update_dpp(0, (int)(m), (ctrl), 0xF, 0xF, true); \
                           if (_d > (m)) (m) = _d; }
#define DPPADDF(s, ctrl) { float _d = __int_as_float(__builtin_amdgcn_update_dpp(0, __float_as_int(s), (ctrl), 0xF, 0xF, true)); \
                           (s) += _d; }
// quad_perm controls: xor1 = [1,0,3,2] = 0xB1 ; xor2 = [2,3,0,1] = 0x4E
#define QP_XOR1 0xB1
#define QP_XOR2 0x4E

__device__ __forceinline__ unsigned orderf(float f) {
    unsigned u = __float_as_uint(f);
    return u ^ (((unsigned)((int)u >> 31)) | 0x80000000u);   // monotone float->uint
}

__device__ __forceinline__ uint2 pick2(uint2 a, uint2 b) {
    // larger key wins; equal key -> smaller index (first-index tiebreak)
    bool takeb = (b.x > a.x) || (b.x == a.x && b.y < a.y);
    return takeb ? b : a;
}

#define REP16(M)  M(0) M(1) M(2) M(3) M(4) M(5) M(6) M(7) M(8) M(9) M(10) M(11) M(12) M(13) M(14) M(15)
#define REP16B(M) M(16) M(17) M(18) M(19) M(20) M(21) M(22) M(23) M(24) M(25) M(26) M(27) M(28) M(29) M(30) M(31)

// Volatile load of 4 consecutive floats: performed exactly once, where written.
#define VLD4(dst, base, c) { const volatile float* _p = (base) + 4*(c); \
    dst.x = _p[0]; dst.y = _p[1]; dst.z = _p[2]; dst.w = _p[3]; }

// -------------------- K1: partial sums of v_src@embs and v_target@embs (coalesced) --------------------
extern "C" __global__ __launch_bounds__(256)
void k_reduce(const float* __restrict__ emb, const float* __restrict__ vsrc,
              const float* __restrict__ vtgt, double* __restrict__ partials)
{
    const int tid = threadIdx.x;
    const int bid = blockIdx.x;
    double aS[4], aT[4];
#pragma unroll
    for (int i = 0; i < 4; i++) { aS[i] = 0.0; aT[i] = 0.0; }

    const float4* emb4 = (const float4*)emb;
    for (long long f = (long long)bid * 256 + tid; f < (long long)M_TOTAL * 4;
         f += (long long)K1_BLOCKS * 256) {
        float4 e = emb4[f];
        long long r = f >> 2;
        float sq = fmaf(e.x, e.x, fmaf(e.y, e.y, fmaf(e.z, e.z, e.w * e.w)));
        DPPADDF(sq, QP_XOR1)
        DPPADDF(sq, QP_XOR2)
        float invn = 1.0f / sqrtf(sq);
        float s = vsrc[r] * invn;
        float t = vtgt[r] * invn;
        aS[0] += (double)(s * e.x); aS[1] += (double)(s * e.y);
        aS[2] += (double)(s * e.z); aS[3] += (double)(s * e.w);
        aT[0] += (double)(t * e.x); aT[1] += (double)(t * e.y);
        aT[2] += (double)(t * e.z); aT[3] += (double)(t * e.w);
    }
#pragma unroll
    for (int i = 0; i < 4; i++) {
#pragma unroll
        for (int off = 32; off >= 4; off >>= 1) {
            aS[i] += __shfl_down(aS[i], off);
            aT[i] += __shfl_down(aT[i], off);
        }
    }
    __shared__ double lred[4][32];
    int lane = tid & 63, wv = tid >> 6;
    if (lane < 4) {
#pragma unroll
        for (int i = 0; i < 4; i++) {
            lred[wv][lane * 4 + i]      = aS[i];
            lred[wv][16 + lane * 4 + i] = aT[i];
        }
    }
    __syncthreads();
    if (tid < 32) {
        double v = lred[0][tid] + lred[1][tid] + lred[2][tid] + lred[3][tid];
        partials[(long long)bid * 32 + tid] = v;
    }
}

// -------------------- K_pre: fused expm (blocks 0..511) + weight re-layout (512..1023) + total zero --------------------
extern "C" __global__ __launch_bounds__(256)
void k_pre(const float* __restrict__ tc, float* __restrict__ Rtab,
           const float* __restrict__ w2g, const float* __restrict__ w3g,
           float* __restrict__ w2R, float* __restrict__ w3R,
           double* __restrict__ totalp)
{
    const int bid = blockIdx.x;
    const int t = threadIdx.x;

    if (bid < 512) {
        // ---- expm(gens[bid]) via 16-term Taylor on the 16x16 skew matrix ----
        const int i = t >> 4, j = t & 15;
        __shared__ float Om[256];
        __shared__ float Ms[256];

        const float* crow = tc + bid * 120;
        float o = 0.0f;
        if (i < j)      o = -crow[(i * (31 - i)) / 2 + (j - i - 1)];
        else if (i > j) o =  crow[(j * (31 - j)) / 2 + (i - j - 1)];
        Om[t] = o;
        Ms[t] = o;
        float s = (i == j ? 1.0f : 0.0f) + o;   // S = I + Omega
        __syncthreads();

#pragma unroll
        for (int k = 2; k <= 16; k++) {
            float a0 = 0.0f, a1 = 0.0f, a2 = 0.0f, a3 = 0.0f;
#pragma unroll
            for (int m = 0; m < 4; m++) {
                a0 = fmaf(Om[i * 16 + m],      Ms[m * 16 + j],        a0);
                a1 = fmaf(Om[i * 16 + 4 + m],  Ms[(4 + m) * 16 + j],  a1);
                a2 = fmaf(Om[i * 16 + 8 + m],  Ms[(8 + m) * 16 + j],  a2);
                a3 = fmaf(Om[i * 16 + 12 + m], Ms[(12 + m) * 16 + j], a3);
            }
            float acc = ((a0 + a1) + (a2 + a3)) * (1.0f / (float)k);
            __syncthreads();
            Ms[t] = acc;
            s += acc;
            __syncthreads();
        }
        Rtab[bid * 256 + t] = s;
    } else {
        // ---- per-thread-contiguous weight layouts for 512-thread k_steps ----
        // k_steps thread tt: L3 needs w3[k][tt], k=0..127 (contiguous).
        //                    L2 (4-lane K-split): c=tt&3, o=tt>>2; q-th weight (q=0..63)
        //                    is w2[2c + 8*(q>>1) + (q&1)][o].
        if (bid == 512 && t == 0) totalp[0] = 0.0;   // zero softmax denominator accumulator
        const int tt = bid - 512;                    // 0..511 = k_steps thread id
        if (t < 128) {
            w3R[tt * 128 + t] = w3g[t * 512 + tt];
        } else if (t < 192) {
            const int q = t - 128;                   // 0..63
            const int kk = 2 * (tt & 3) + 8 * (q >> 1) + (q & 1);
            w2R[tt * 64 + q] = w2g[kk * 128 + (tt >> 2)];
        }
    }
}

// -------------------- K2: the sequential 64-step scan (1 block, 512 threads) --------------------
// R4 base (208us proven) with:
//  - L2 as 4-lane K-split: per-lane ds_read_b64 multipliers + quad_perm DPP reduce -> h2s direct
//  - L3 multipliers via chunked 2-deep-pipelined LDS uniform broadcasts (bounded 32-VGPR transient)
//  - w1 in LDS (frees 16 VGPRs to keep peak live set under the 256 unified budget)
extern "C" __global__ __launch_bounds__(512)
__attribute__((amdgpu_waves_per_eu(2, 2)))
void k_steps(const double* __restrict__ partials,
             const float* __restrict__ w1g, const float* __restrict__ b1g,
             const float* __restrict__ b2g, const float* __restrict__ b3g,
             const float* __restrict__ w2R, const float* __restrict__ w3R,
             const float* __restrict__ Rtab, const float* __restrict__ gum,
             const int* __restrict__ nsp,
             float* __restrict__ outL, float* __restrict__ vf_out)
{
    __shared__ __align__(16) float w1s[16 * 256];
    __shared__ __align__(16) float h1s[256];
    __shared__ __align__(16) float h2s[128];
    __shared__ float xs[32];
    __shared__ float b2s[128];
    __shared__ uint2 kidx[8];
    __shared__ double dred[512];

    const int t = threadIdx.x;
    const int lane = t & 63;
    const int wv = t >> 6;
    const int c4 = t & 3;             // L2 quad lane
    const int c1 = t & 255;           // L1 output column

    // ---- register-resident weights via volatile one-time loads ----
    const volatile float* w3v = (const volatile float*)(w3R + (size_t)t * 128);
    const volatile float* w2v = (const volatile float*)(w2R + (size_t)t * 64);
#define W3D(c) float4 w3_##c; VLD4(w3_##c, w3v, c)
    REP16(W3D) REP16B(W3D)
#undef W3D
#define W2D(c) float4 w2_##c; VLD4(w2_##c, w2v, c)
    REP16(W2D)
#undef W2D
    const float b3r = b3g[t];

    // stage w1 v-half rows + b2 into LDS
    for (int i = t; i < 16 * 256; i += 512) w1s[i] = w1g[i];
    if (t < 128) b2s[t] = b2g[t];

    // warm Rtab (512 KB) into this XCD's L2 so per-step rotation loads hit L2 not HBM
    float warm = 0.0f;
    for (int i = t; i < 512 * 256 / 4; i += 512) {
        float4 rv = ((const float4*)Rtab)[i];
        warm += (rv.x + rv.y) + (rv.z + rv.w);
    }

    // stage-2 reduce of K1 partials, coalesced: flat[f] has column f%32
    {
        double v = 0.0;
#pragma unroll 4
        for (int i = 0; i < (K1_BLOCKS * 32) / 512; i++) v += partials[i * 512 + t];
        dred[t] = v;
    }

    int ns = nsp[0];
    if (ns > 64) ns = 64;
    if (ns < 0)  ns = 0;
    if (ns == -2147483647) vf_out[0] = warm;   // never true; defeats DCE

    __syncthreads();
    if (t < 32) {
        double s = 0.0;
#pragma unroll
        for (int j = 0; j < 16; j++) s += dred[t + 32 * j];
        xs[t] = (float)s;                      // xs[0:16]=v_cur, xs[16:32]=v_tgt
    }
    __syncthreads();

    // b1_eff = b1 + v_tgt @ w1[16:32]; v replicated per-wave (waves 0-3 only)
    float b1e = 0.0f, vreg = 0.0f;
    if (t < 256) {
        float a = b1g[c1];
#pragma unroll
        for (int m = 0; m < 16; m++)
            a = fmaf(xs[16 + m], w1g[(16 + m) * 256 + c1], a);
        b1e = a;
        vreg = xs[lane & 15];        // lane l holds v[l&15]
    }

    if (ns == 0 && t < 16) vf_out[t] = xs[t];

    for (int step = 0; step < ns; step++) {
        float gv = gum[step * 512 + t];       // hoisted global load (needed at argmax)

        // ---- layer 1: h1 = relu(v @ w1[0:16] + b1_eff); waves 0-3, v in own-wave regs ----
        if (t < 256) {
            float a0 = 0.0f, a1 = 0.0f;
#pragma unroll
            for (int m = 0; m < 8; m++) {
                a0 = fmaf(rlf(vreg, m),     w1s[m * 256 + t],       a0);
                a1 = fmaf(rlf(vreg, 8 + m), w1s[(8 + m) * 256 + t], a1);
            }
            h1s[t] = fmaxf((a0 + a1) + b1e, 0.0f);
        }
        bar_lds();

        // ---- layer 2: 128 outputs, 4-lane K-split. lane c of quad o=t>>2 covers
        //      k = 2c + 64ch + 8j (+1): conflict-free ds_read_b64 (4 distinct addrs,
        //      16-way broadcast each), quad_perm DPP reduce, +b2, relu -> h2s. ----
        {
            const float2* h1b = (const float2*)h1s;
            float a0 = 0.0f, a1 = 0.0f, a2 = 0.0f, a3 = 0.0f;
            float2 nA0, nA1, nA2, nA3, nA4, nA5, nA6, nA7;
            float2 nB0, nB1, nB2, nB3, nB4, nB5, nB6, nB7;
#define L2LD(R, ch) \
            (R##0) = h1b[c4 + 32*(ch) +  0]; (R##1) = h1b[c4 + 32*(ch) +  4]; \
            (R##2) = h1b[c4 + 32*(ch) +  8]; (R##3) = h1b[c4 + 32*(ch) + 12]; \
            (R##4) = h1b[c4 + 32*(ch) + 16]; (R##5) = h1b[c4 + 32*(ch) + 20]; \
            (R##6) = h1b[c4 + 32*(ch) + 24]; (R##7) = h1b[c4 + 32*(ch) + 28];
#define L2CH(R, W0, W1, Wa, Wb) \
            a0 = fmaf((R##0).x, W0.x, a0); a1 = fmaf((R##0).y, W0.y, a1); \
            a2 = fmaf((R##1).x, W0.z, a2); a3 = fmaf((R##1).y, W0.w, a3); \
            a0 = fmaf((R##2).x, W1.x, a0); a1 = fmaf((R##2).y, W1.y, a1); \
            a2 = fmaf((R##3).x, W1.z, a2); a3 = fmaf((R##3).y, W1.w, a3); \
            a0 = fmaf((R##4).x, Wa.x, a0); a1 = fmaf((R##4).y, Wa.y, a1); \
            a2 = fmaf((R##5).x, Wa.z, a2); a3 = fmaf((R##5).y, Wa.w, a3); \
            a0 = fmaf((R##6).x, Wb.x, a0); a1 = fmaf((R##6).y, Wb.y, a1); \
            a2 = fmaf((R##7).x, Wb.z, a2); a3 = fmaf((R##7).y, Wb.w, a3);
            L2LD(nA, 0)
            L2LD(nB, 1)
            L2CH(nA, w2_0,  w2_1,  w2_2,  w2_3)
            L2LD(nA, 2)
            L2CH(nB, w2_4,  w2_5,  w2_6,  w2_7)
            L2LD(nB, 3)
            L2CH(nA, w2_8,  w2_9,  w2_10, w2_11)
            L2CH(nB, w2_12, w2_13, w2_14, w2_15)
#undef L2LD
#undef L2CH
            float asum = (a0 + a1) + (a2 + a3);
            DPPADDF(asum, QP_XOR1)
            DPPADDF(asum, QP_XOR2)           // all 4 quad lanes now hold the 256-K sum
            if (c4 == 0) h2s[t >> 2] = fmaxf(asum + b2s[t >> 2], 0.0f);
        }
        bar_lds();

        // ---- layer 3: logits = h2 @ w3 + b3; multipliers via chunked LDS uniform
        //      broadcasts (2-deep pipeline, bounded 32-VGPR transient) ----
        float lg;
        {
            const float2* h2b = (const float2*)h2s;
            float lg0 = 0.0f, lg1 = 0.0f, lg2 = 0.0f, lg3 = 0.0f;
            float2 mA0, mA1, mA2, mA3, mA4, mA5, mA6, mA7;
            float2 mB0, mB1, mB2, mB3, mB4, mB5, mB6, mB7;
#define L3LD(R, ch) \
            (R##0) = h2b[8*(ch) + 0]; (R##1) = h2b[8*(ch) + 1]; \
            (R##2) = h2b[8*(ch) + 2]; (R##3) = h2b[8*(ch) + 3]; \
            (R##4) = h2b[8*(ch) + 4]; (R##5) = h2b[8*(ch) + 5]; \
            (R##6) = h2b[8*(ch) + 6]; (R##7) = h2b[8*(ch) + 7];
#define L3CH(R, W0, W1, Wa, Wb) \
            lg0 = fmaf((R##0).x, W0.x, lg0); lg1 = fmaf((R##0).y, W0.y, lg1); \
            lg2 = fmaf((R##1).x, W0.z, lg2); lg3 = fmaf((R##1).y, W0.w, lg3); \
            lg0 = fmaf((R##2).x, W1.x, lg0); lg1 = fmaf((R##2).y, W1.y, lg1); \
            lg2 = fmaf((R##3).x, W1.z, lg2); lg3 = fmaf((R##3).y, W1.w, lg3); \
            lg0 = fmaf((R##4).x, Wa.x, lg0); lg1 = fmaf((R##4).y, Wa.y, lg1); \
            lg2 = fmaf((R##5).x, Wa.z, lg2); lg3 = fmaf((R##5).y, Wa.w, lg3); \
            lg0 = fmaf((R##6).x, Wb.x, lg0); lg1 = fmaf((R##6).y, Wb.y, lg1); \
            lg2 = fmaf((R##7).x, Wb.z, lg2); lg3 = fmaf((R##7).y, Wb.w, lg3);
            L3LD(mA, 0)
            L3LD(mB, 1)
            L3CH(mA, w3_0,  w3_1,  w3_2,  w3_3)
            L3LD(mA, 2)
            L3CH(mB, w3_4,  w3_5,  w3_6,  w3_7)
            L3LD(mB, 3)
            L3CH(mA, w3_8,  w3_9,  w3_10, w3_11)
            L3LD(mA, 4)
            L3CH(mB, w3_12, w3_13, w3_14, w3_15)
            L3LD(mB, 5)
            L3CH(mA, w3_16, w3_17, w3_18, w3_19)
            L3LD(mA, 6)
            L3CH(mB, w3_20, w3_21, w3_22, w3_23)
            L3LD(mB, 7)
            L3CH(mA, w3_24, w3_25, w3_26, w3_27)
            L3CH(mB, w3_28, w3_29, w3_30, w3_31)
#undef L3LD
#undef L3CH
            lg = ((lg0 + lg1) + (lg2 + lg3)) + b3r;
        }
        outL[step * 512 + t] = lg;   // fire-and-forget; lgkm barriers don't drain vmcnt

        // ---- argmax(logits + gumbel): DPP wave-max + ballot (no bpermute chain) ----
        {
            unsigned ok = orderf(lg + gv);
            unsigned m = ok;
            DPPMAXU(m, 0x111)   // row_shr:1
            DPPMAXU(m, 0x112)   // row_shr:2
            DPPMAXU(m, 0x114)   // row_shr:4
            DPPMAXU(m, 0x118)   // row_shr:8  -> lane15 of each row has row max
            DPPMAXU(m, 0x142)   // row_bcast15
            DPPMAXU(m, 0x143)   // row_bcast31 -> lane63 has wave max
            unsigned wmax = (unsigned)__builtin_amdgcn_readlane((int)m, 63);
            unsigned long long mask = __ballot(ok == wmax);
            if (lane == 0) {
                uint2 kv; kv.x = wmax; kv.y = (unsigned)(wv * 64 + (__ffsll(mask) - 1));
                kidx[wv] = kv;
            }
        }
        bar_lds();

        // ---- rotation: waves 0-3, lanes 0-15; v' = normalize(R[bi] @ v), no shuffles ----
        if (t < 256 && lane < 16) {
            uint2 K0, K1, K2, K3, K4, K5, K6, K7;
            { uint4 a = *(const uint4*)&kidx[0]; K0.x=a.x; K0.y=a.y; K1.x=a.z; K1.y=a.w; }
            { uint4 a = *(const uint4*)&kidx[2]; K2.x=a.x; K2.y=a.y; K3.x=a.z; K3.y=a.w; }
            { uint4 a = *(const uint4*)&kidx[4]; K4.x=a.x; K4.y=a.y; K5.x=a.z; K5.y=a.w; }
            { uint4 a = *(const uint4*)&kidx[6]; K6.x=a.x; K6.y=a.y; K7.x=a.z; K7.y=a.w; }
            uint2 w01 = pick2(K0, K1), w23 = pick2(K2, K3);
            uint2 w45 = pick2(K4, K5), w67 = pick2(K6, K7);
            uint2 win = pick2(pick2(w01, w23), pick2(w45, w67));
            const int bi = (int)win.y;

            const float4* rp = (const float4*)(Rtab + (size_t)bi * 256 + lane * 16);
            float4 ra = rp[0], rb = rp[1], rc = rp[2], rd = rp[3];
            // 4 independent chains, then tree-sum
            float p0 = ra.x * rlf(vreg, 0);
            float p1 = rb.x * rlf(vreg, 4);
            float p2r = rc.x * rlf(vreg, 8);
            float p3 = rd.x * rlf(vreg, 12);
            p0 = fmaf(ra.y, rlf(vreg, 1), p0);
            p1 = fmaf(rb.y, rlf(vreg, 5), p1);
            p2r = fmaf(rc.y, rlf(vreg, 9), p2r);
            p3 = fmaf(rd.y, rlf(vreg, 13), p3);
            p0 = fmaf(ra.z, rlf(vreg, 2), p0);
            p1 = fmaf(rb.z, rlf(vreg, 6), p1);
            p2r = fmaf(rc.z, rlf(vreg, 10), p2r);
            p3 = fmaf(rd.z, rlf(vreg, 14), p3);
            p0 = fmaf(ra.w, rlf(vreg, 3), p0);
            p1 = fmaf(rb.w, rlf(vreg, 7), p1);
            p2r = fmaf(rc.w, rlf(vreg, 11), p2r);
            p3 = fmaf(rd.w, rlf(vreg, 15), p3);
            float pr = (p0 + p1) + (p2r + p3);

            float s2 = pr * pr;                 // sum over lanes 0-15 via DPP row-shr
            DPPADDF(s2, 0x111)
            DPPADDF(s2, 0x112)
            DPPADDF(s2, 0x114)
            DPPADDF(s2, 0x118)                  // lane15 = full row sum
            float n2 = rlf(s2, 15);
            float invn = 1.0f / sqrtf(n2);
            vreg = pr * invn;                   // lane l holds v'[l], waves 0-3 consistent
            if (step == ns - 1 && t < 16) vf_out[t] = vreg;
        }
        // no barrier here: next L1 uses only own-wave registers; h1s writes are
        // separated from this step's readers by the barriers above.
    }
}

// -------------------- K3: scores = exp(dot(v_fin, emb_row_norm)); block sums -> atomic total --------------------
extern "C" __global__ __launch_bounds__(256)
void k_scores(const float* __restrict__ emb, const float* __restrict__ vf16,
              float* __restrict__ outP, double* __restrict__ totalp)
{
    __shared__ float vfs[16];
    const int tid = threadIdx.x;
    const int bid = blockIdx.x;
    const int q = tid & 3;
    if (tid < 16) vfs[tid] = vf16[tid];
    __syncthreads();
    float v0 = vfs[q * 4 + 0], v1 = vfs[q * 4 + 1], v2 = vfs[q * 4 + 2], v3 = vfs[q * 4 + 3];

    const float4* emb4 = (const float4*)emb;
    double bsum = 0.0;
    for (long long f = (long long)bid * 256 + tid; f < (long long)M_TOTAL * 4;
         f += (long long)K3_BLOCKS * 256) {
        float4 e = emb4[f];
        long long r = f >> 2;
        float sq = fmaf(e.x, e.x, fmaf(e.y, e.y, fmaf(e.z, e.z, e.w * e.w)));
        float d  = fmaf(e.x, v0, fmaf(e.y, v1, fmaf(e.z, v2, e.w * v3)));
        DPPADDF(sq, QP_XOR1)
        DPPADDF(d,  QP_XOR1)
        DPPADDF(sq, QP_XOR2)
        DPPADDF(d,  QP_XOR2)
        float ex = expf(d / sqrtf(sq));   // |score| <= 1, no overflow; softmax shift cancels
        if (q == 0) {
            outP[r] = ex;
            bsum += (double)ex;
        }
    }
#pragma unroll
    for (int off = 4; off <= 32; off <<= 1) bsum += __shfl_down(bsum, off);
    __shared__ double lred[4];
    if ((tid & 63) == 0) lred[tid >> 6] = bsum;
    __syncthreads();
    if (tid == 0) atomicAdd(totalp, lred[0] + lred[1] + lred[2] + lred[3]);
}

// -------------------- K5: normalize --------------------
extern "C" __global__ __launch_bounds__(256)
void k_scale(float* __restrict__ outP, const double* __restrict__ totalp)
{
    const float inv = 1.0f / (float)totalp[0];
    long long r4 = (long long)blockIdx.x * 256 + threadIdx.x;
    if (r4 < M_TOTAL / 4) {
        float4* p = (float4*)outP;
        float4 v = p[r4];
        v.x *= inv; v.y *= inv; v.z *= inv; v.w *= inv;
        p[r4] = v;
    }
}

extern "C" void kernel_launch(void* const* d_in, const int* in_sizes, int n_in,
                              void* d_out, int out_size, void* d_ws, size_t ws_size,
                              hipStream_t stream)
{
    const float* vsrc = (const float*)d_in[0];
    const float* vtgt = (const float*)d_in[1];
    const float* emb  = (const float*)d_in[2];
    const float* tc   = (const float*)d_in[3];
    // d_in[4] = bases: structure is hard-coded (omega[i][j] = -/+ coeffs[t*, k(i,j)])
    const float* w1 = (const float*)d_in[5];
    const float* b1 = (const float*)d_in[6];
    const float* w2 = (const float*)d_in[7];
    const float* b2 = (const float*)d_in[8];
    const float* w3 = (const float*)d_in[9];
    const float* b3 = (const float*)d_in[10];
    const float* gum = (const float*)d_in[11];
    const int* nsp   = (const int*)d_in[12];

    float* outP = (float*)d_out;          // pred_marking [2M]
    float* outL = outP + M_TOTAL;         // logits [64*512]

    double* wsd      = (double*)d_ws;
    double* partials = wsd;                         // 1024*32 doubles (region sized for 2048*32)
    double* totalp   = wsd + 2048 * 32;             // 1 double
    float*  vf       = (float*)(totalp + 1);        // 16 floats

    // Scratch tables live in the pred_marking output region; fully consumed by
    // k_steps before k_scores/k_scale overwrite outP.
    float* Rtab = outP;                   // 512*256 = 131072 floats
    float* w3R  = outP + 131072;          // 512*128 =  65536 floats
    float* w2R  = outP + 196608;          // 512*64  =  32768 floats

    k_pre<<<1024, 256, 0, stream>>>(tc, Rtab, w2, w3, w2R, w3R, totalp);
    k_reduce<<<K1_BLOCKS, 256, 0, stream>>>(emb, vsrc, vtgt, partials);
    k_steps<<<1, 512, 0, stream>>>(partials, w1, b1, b2, b3, w2R, w3R, Rtab, gum, nsp, outL, vf);
    k_scores<<<K3_BLOCKS, 256, 0, stream>>>(emb, vf, outP, totalp);
    k_scale<<<(M_TOTAL / 4 + 255) / 256, 256, 0, stream>>>(outP, totalp);
}

// Round 8
// 461.762 us; speedup vs baseline: 1.4040x; 1.4040x over previous
//
#include <hip/hip_runtime.h>

#define M_TOTAL   2000000
#define NT        512
#define K1_BLOCKS 1024
#define K3_BLOCKS 2048

__device__ __forceinline__ float rlf(float v, int l) {
    union { float f; int i; } u; u.f = v;
    u.i = __builtin_amdgcn_readlane(u.i, l);
    return u.f;
}

// Barrier with LDS-only drain: in-loop cross-thread data is exclusively LDS,
// so vmcnt (global outL stores / gum / Rtab loads) never needs draining.
__device__ __forceinline__ void bar_lds() {
    asm volatile("s_waitcnt lgkmcnt(0)" ::: "memory");
    __builtin_amdgcn_s_barrier();
    asm volatile("" ::: "memory");
}

// DPP helpers (register-crossbar cross-lane, ~4cy vs ~100cy for ds_bpermute shuffles).
#define DPPMAXU(m, ctrl) { unsigned _d = (unsigned)__builtin_amdgcn_update_dpp(0, (int)(m), (ctrl), 0xF, 0xF, true); \
                           if (_d > (m)) (m) = _d; }
#define DPPADDF(s, ctrl) { float _d = __int_as_float(__builtin_amdgcn_update_dpp(0, __float_as_int(s), (ctrl), 0xF, 0xF, true)); \
                           (s) += _d; }
// quad_perm controls: xor1 = [1,0,3,2] = 0xB1 ; xor2 = [2,3,0,1] = 0x4E
#define QP_XOR1 0xB1
#define QP_XOR2 0x4E

__device__ __forceinline__ unsigned orderf(float f) {
    unsigned u = __float_as_uint(f);
    return u ^ (((unsigned)((int)u >> 31)) | 0x80000000u);   // monotone float->uint
}

__device__ __forceinline__ uint2 pick2(uint2 a, uint2 b) {
    // larger key wins; equal key -> smaller index (first-index tiebreak)
    bool takeb = (b.x > a.x) || (b.x == a.x && b.y < a.y);
    return takeb ? b : a;
}

#define REP16(M)  M(0) M(1) M(2) M(3) M(4) M(5) M(6) M(7) M(8) M(9) M(10) M(11) M(12) M(13) M(14) M(15)
#define REP16B(M) M(16) M(17) M(18) M(19) M(20) M(21) M(22) M(23) M(24) M(25) M(26) M(27) M(28) M(29) M(30) M(31)

// Volatile load of 4 consecutive floats: performed exactly once, where written.
#define VLD4(dst, base, c) { const volatile float* _p = (base) + 4*(c); \
    dst.x = _p[0]; dst.y = _p[1]; dst.z = _p[2]; dst.w = _p[3]; }

// -------------------- K_front: fused reduce (blocks 0..1023) + expm (1024..1535) + relayout (1536..2051) --------------------
extern "C" __global__ __launch_bounds__(256)
void k_front(const float* __restrict__ emb, const float* __restrict__ vsrc,
             const float* __restrict__ vtgt, double* __restrict__ partials,
             const float* __restrict__ tc, float* __restrict__ Rtab,
             const float* __restrict__ w2g, const float* __restrict__ w3g,
             float* __restrict__ w2R, float* __restrict__ w3R,
             double* __restrict__ totalp)
{
    const int bid = blockIdx.x;
    const int t = threadIdx.x;

    if (bid < K1_BLOCKS) {
        // ---- partial sums of v_src@embs and v_target@embs (coalesced, f32 accum:
        //      only ~31 terms/accumulator so f32 is exact to ~1e-6; halves the VALU) ----
        float aS[4], aT[4];
#pragma unroll
        for (int i = 0; i < 4; i++) { aS[i] = 0.0f; aT[i] = 0.0f; }

        const float4* emb4 = (const float4*)emb;
        for (long long f = (long long)bid * 256 + t; f < (long long)M_TOTAL * 4;
             f += (long long)K1_BLOCKS * 256) {
            float4 e = emb4[f];
            long long r = f >> 2;
            float sq = fmaf(e.x, e.x, fmaf(e.y, e.y, fmaf(e.z, e.z, e.w * e.w)));
            DPPADDF(sq, QP_XOR1)
            DPPADDF(sq, QP_XOR2)
            float invn = 1.0f / sqrtf(sq);
            float s = vsrc[r] * invn;
            float tv = vtgt[r] * invn;
            aS[0] = fmaf(s, e.x, aS[0]);  aS[1] = fmaf(s, e.y, aS[1]);
            aS[2] = fmaf(s, e.z, aS[2]);  aS[3] = fmaf(s, e.w, aS[3]);
            aT[0] = fmaf(tv, e.x, aT[0]); aT[1] = fmaf(tv, e.y, aT[1]);
            aT[2] = fmaf(tv, e.z, aT[2]); aT[3] = fmaf(tv, e.w, aT[3]);
        }
        double dS[4], dT[4];
#pragma unroll
        for (int i = 0; i < 4; i++) { dS[i] = (double)aS[i]; dT[i] = (double)aT[i]; }
#pragma unroll
        for (int i = 0; i < 4; i++) {
#pragma unroll
            for (int off = 32; off >= 4; off >>= 1) {
                dS[i] += __shfl_down(dS[i], off);
                dT[i] += __shfl_down(dT[i], off);
            }
        }
        __shared__ double lred[4][32];
        int lane = t & 63, wv = t >> 6;
        if (lane < 4) {
#pragma unroll
            for (int i = 0; i < 4; i++) {
                lred[wv][lane * 4 + i]      = dS[i];
                lred[wv][16 + lane * 4 + i] = dT[i];
            }
        }
        __syncthreads();
        if (t < 32) {
            double v = lred[0][t] + lred[1][t] + lred[2][t] + lred[3][t];
            partials[(long long)bid * 32 + t] = v;
        }
    } else if (bid < K1_BLOCKS + 512) {
        // ---- expm(gens[b]) via 16-term Taylor on the 16x16 skew matrix ----
        const int b = bid - K1_BLOCKS;
        const int i = t >> 4, j = t & 15;
        __shared__ float Om[256];
        __shared__ float Ms[256];

        const float* crow = tc + b * 120;
        float o = 0.0f;
        if (i < j)      o = -crow[(i * (31 - i)) / 2 + (j - i - 1)];
        else if (i > j) o =  crow[(j * (31 - j)) / 2 + (i - j - 1)];
        Om[t] = o;
        Ms[t] = o;
        float s = (i == j ? 1.0f : 0.0f) + o;   // S = I + Omega
        __syncthreads();

#pragma unroll
        for (int k = 2; k <= 16; k++) {
            float a0 = 0.0f, a1 = 0.0f, a2 = 0.0f, a3 = 0.0f;
#pragma unroll
            for (int m = 0; m < 4; m++) {
                a0 = fmaf(Om[i * 16 + m],      Ms[m * 16 + j],        a0);
                a1 = fmaf(Om[i * 16 + 4 + m],  Ms[(4 + m) * 16 + j],  a1);
                a2 = fmaf(Om[i * 16 + 8 + m],  Ms[(8 + m) * 16 + j],  a2);
                a3 = fmaf(Om[i * 16 + 12 + m], Ms[(12 + m) * 16 + j], a3);
            }
            float acc = ((a0 + a1) + (a2 + a3)) * (1.0f / (float)k);
            __syncthreads();
            Ms[t] = acc;
            s += acc;
            __syncthreads();
        }
        Rtab[b * 256 + t] = s;
    } else {
        // ---- per-thread-contiguous weight layouts for 512-thread k_steps (R4 layout) ----
        // thread tt of k_steps: w3R[tt*128 + k] = w3[k][tt], k=0..127
        //                       w2R[tt*64 + m]  = w2[64*(tt>>7) + m][tt&127], m=0..63
        const int b = bid - (K1_BLOCKS + 512);   // 0..515
        if (b == 0 && t == 0) totalp[0] = 0.0;   // zero softmax denominator accumulator
        if (t >= 128) return;
        const int k = t;
        if (b < 512) {
            w3R[b * 128 + k] = w3g[k * 512 + b];
        } else {
            const int p2 = b - 512;     // 0..3
            const int j2 = k;           // 0..127
            for (int m = 0; m < 64; m++)
                w2R[(((p2 << 7) | j2) * 64) + m] = w2g[(64 * p2 + m) * 128 + j2];
        }
    }
}

// -------------------- K2: the sequential 64-step scan (1 block, 512 threads) --------------------
// R4-exact structure (proven 208us): register-resident w2/w3 + readlane broadcasts,
// DPP+ballot argmax, shuffle-free rotation, 3 lgkm-only barriers/step.
extern "C" __global__ __launch_bounds__(512)
__attribute__((amdgpu_waves_per_eu(2, 2)))
void k_steps(const double* __restrict__ partials,
             const float* __restrict__ w1g, const float* __restrict__ b1g,
             const float* __restrict__ b2g, const float* __restrict__ b3g,
             const float* __restrict__ w2R, const float* __restrict__ w3R,
             const float* __restrict__ Rtab, const float* __restrict__ gum,
             const int* __restrict__ nsp,
             float* __restrict__ outL, float* __restrict__ vf_out)
{
    __shared__ __align__(16) float h1s[256];
    __shared__ __align__(16) float h2p[512];
    __shared__ __align__(16) float h2s[128];
    __shared__ float xs[32];
    __shared__ float b2s[128];
    __shared__ uint2 kidx[8];
    __shared__ double dred[512];

    const int t = threadIdx.x;
    const int lane = t & 63;
    const int wv = t >> 6;
    const int j2 = t & 127, p2 = t >> 7;
    const int c1 = t & 255;           // L1 output column (threads 256-511 shadow 0-255)

    // ---- register-resident weights via volatile one-time loads ----
    const volatile float* w3v = (const volatile float*)(w3R + (size_t)t * 128);
    const volatile float* w2v = (const volatile float*)(w2R + (size_t)t * 64);
#define W3D(c) float4 w3_##c; VLD4(w3_##c, w3v, c)
    REP16(W3D) REP16B(W3D)
#undef W3D
#define W2D(c) float4 w2_##c; VLD4(w2_##c, w2v, c)
    REP16(W2D)
#undef W2D
    const float b3r = b3g[t];

    // w1 v-half columns in registers (16 floats, static indexing only)
    float w1r[16];
    {
        const volatile float* w1v = (const volatile float*)w1g;
#pragma unroll
        for (int m = 0; m < 16; m++) w1r[m] = w1v[m * 256 + c1];
    }
    if (t < 128) b2s[t] = b2g[t];

    // warm Rtab (512 KB) into this XCD's L2 so per-step rotation loads hit L2 not HBM
    float warm = 0.0f;
    for (int i = t; i < 512 * 256 / 4; i += 512) {
        float4 rv = ((const float4*)Rtab)[i];
        warm += (rv.x + rv.y) + (rv.z + rv.w);
    }

    // stage-2 reduce of K1 partials, coalesced: flat[f] has column f%32
    {
        double v = 0.0;
#pragma unroll 4
        for (int i = 0; i < (K1_BLOCKS * 32) / 512; i++) v += partials[i * 512 + t];
        dred[t] = v;
    }

    int ns = nsp[0];
    if (ns > 64) ns = 64;
    if (ns < 0)  ns = 0;
    if (ns == -2147483647) vf_out[0] = warm;   // never true; defeats DCE

    __syncthreads();
    if (t < 32) {
        double s = 0.0;
#pragma unroll
        for (int j = 0; j < 16; j++) s += dred[t + 32 * j];
        xs[t] = (float)s;                      // xs[0:16]=v_cur, xs[16:32]=v_tgt
    }
    __syncthreads();

    // b1_eff = b1 + v_tgt @ w1[16:32]; v replicated per-wave (waves 0-3 only)
    float b1e = 0.0f, vreg = 0.0f;
    if (t < 256) {
        float a = b1g[c1];
#pragma unroll
        for (int m = 0; m < 16; m++)
            a = fmaf(xs[16 + m], w1g[(16 + m) * 256 + c1], a);
        b1e = a;
        vreg = xs[lane & 15];        // lane l holds v[l&15]
    }

    if (ns == 0 && t < 16) vf_out[t] = xs[t];

    for (int step = 0; step < ns; step++) {
        float gv = gum[step * 512 + t];       // hoisted global load (needed at argmax)

        // ---- layer 1: h1 = relu(v @ w1[0:16] + b1_eff); waves 0-3, v in own-wave regs ----
        if (t < 256) {
            float a0 = 0.0f, a1 = 0.0f;
#pragma unroll
            for (int m = 0; m < 8; m++) {
                a0 = fmaf(rlf(vreg, m),     w1r[m],     a0);
                a1 = fmaf(rlf(vreg, 8 + m), w1r[8 + m], a1);
            }
            h1s[t] = fmaxf((a0 + a1) + b1e, 0.0f);
        }
        bar_lds();

        // ---- layer 2 partials: 128 outputs x 4-way K split ----
        {
            float h1seg = h1s[(p2 << 6) | lane];
            float a0 = 0.0f, a1 = 0.0f, a2 = 0.0f, a3 = 0.0f;
#define L2C(c) { a0 = fmaf(rlf(h1seg, 4*(c)+0), w2_##c.x, a0); \
                 a1 = fmaf(rlf(h1seg, 4*(c)+1), w2_##c.y, a1); \
                 a2 = fmaf(rlf(h1seg, 4*(c)+2), w2_##c.z, a2); \
                 a3 = fmaf(rlf(h1seg, 4*(c)+3), w2_##c.w, a3); }
            REP16(L2C)
#undef L2C
            h2p[(p2 << 7) | j2] = (a0 + a1) + (a2 + a3);
        }
        bar_lds();

        // ---- layer 3: reconstruct h2 in-lane (fused reduce), then logits ----
        float lg;
        {
            float h2lo = fmaxf(((h2p[lane] + h2p[128 + lane]) +
                                (h2p[256 + lane] + h2p[384 + lane])) + b2s[lane], 0.0f);
            float h2hi = fmaxf(((h2p[64 + lane] + h2p[192 + lane]) +
                                (h2p[320 + lane] + h2p[448 + lane])) + b2s[64 + lane], 0.0f);
            float lg0 = 0.0f, lg1 = 0.0f, lg2 = 0.0f, lg3 = 0.0f;
#define L3LO(c) { lg0 = fmaf(rlf(h2lo, 4*(c)+0), w3_##c.x, lg0); \
                  lg1 = fmaf(rlf(h2lo, 4*(c)+1), w3_##c.y, lg1); \
                  lg2 = fmaf(rlf(h2lo, 4*(c)+2), w3_##c.z, lg2); \
                  lg3 = fmaf(rlf(h2lo, 4*(c)+3), w3_##c.w, lg3); }
#define L3HI(c) { lg0 = fmaf(rlf(h2hi, 4*(c)-64), w3_##c.x, lg0); \
                  lg1 = fmaf(rlf(h2hi, 4*(c)-63), w3_##c.y, lg1); \
                  lg2 = fmaf(rlf(h2hi, 4*(c)-62), w3_##c.z, lg2); \
                  lg3 = fmaf(rlf(h2hi, 4*(c)-61), w3_##c.w, lg3); }
            REP16(L3LO) REP16B(L3HI)
#undef L3LO
#undef L3HI
            lg = ((lg0 + lg1) + (lg2 + lg3)) + b3r;
        }
        outL[step * 512 + t] = lg;   // fire-and-forget; lgkm barriers don't drain vmcnt
        (void)h2s;

        // ---- argmax(logits + gumbel): DPP wave-max + ballot (no bpermute chain) ----
        {
            unsigned ok = orderf(lg + gv);
            unsigned m = ok;
            DPPMAXU(m, 0x111)   // row_shr:1
            DPPMAXU(m, 0x112)   // row_shr:2
            DPPMAXU(m, 0x114)   // row_shr:4
            DPPMAXU(m, 0x118)   // row_shr:8  -> lane15 of each row has row max
            DPPMAXU(m, 0x142)   // row_bcast15
            DPPMAXU(m, 0x143)   // row_bcast31 -> lane63 has wave max
            unsigned wmax = (unsigned)__builtin_amdgcn_readlane((int)m, 63);
            unsigned long long mask = __ballot(ok == wmax);
            if (lane == 0) {
                uint2 kv; kv.x = wmax; kv.y = (unsigned)(wv * 64 + (__ffsll(mask) - 1));
                kidx[wv] = kv;
            }
        }
        bar_lds();

        // ---- rotation: waves 0-3, lanes 0-15; v' = normalize(R[bi] @ v), no shuffles ----
        if (t < 256 && lane < 16) {
            uint2 K0, K1, K2, K3, K4, K5, K6, K7;
            { uint4 a = *(const uint4*)&kidx[0]; K0.x=a.x; K0.y=a.y; K1.x=a.z; K1.y=a.w; }
            { uint4 a = *(const uint4*)&kidx[2]; K2.x=a.x; K2.y=a.y; K3.x=a.z; K3.y=a.w; }
            { uint4 a = *(const uint4*)&kidx[4]; K4.x=a.x; K4.y=a.y; K5.x=a.z; K5.y=a.w; }
            { uint4 a = *(const uint4*)&kidx[6]; K6.x=a.x; K6.y=a.y; K7.x=a.z; K7.y=a.w; }
            uint2 w01 = pick2(K0, K1), w23 = pick2(K2, K3);
            uint2 w45 = pick2(K4, K5), w67 = pick2(K6, K7);
            uint2 win = pick2(pick2(w01, w23), pick2(w45, w67));
            const int bi = (int)win.y;

            const float4* rp = (const float4*)(Rtab + (size_t)bi * 256 + lane * 16);
            float4 ra = rp[0], rb = rp[1], rc = rp[2], rd = rp[3];
            // 4 independent chains, then tree-sum
            float p0 = ra.x * rlf(vreg, 0);
            float p1 = rb.x * rlf(vreg, 4);
            float p2r = rc.x * rlf(vreg, 8);
            float p3 = rd.x * rlf(vreg, 12);
            p0 = fmaf(ra.y, rlf(vreg, 1), p0);
            p1 = fmaf(rb.y, rlf(vreg, 5), p1);
            p2r = fmaf(rc.y, rlf(vreg, 9), p2r);
            p3 = fmaf(rd.y, rlf(vreg, 13), p3);
            p0 = fmaf(ra.z, rlf(vreg, 2), p0);
            p1 = fmaf(rb.z, rlf(vreg, 6), p1);
            p2r = fmaf(rc.z, rlf(vreg, 10), p2r);
            p3 = fmaf(rd.z, rlf(vreg, 14), p3);
            p0 = fmaf(ra.w, rlf(vreg, 3), p0);
            p1 = fmaf(rb.w, rlf(vreg, 7), p1);
            p2r = fmaf(rc.w, rlf(vreg, 11), p2r);
            p3 = fmaf(rd.w, rlf(vreg, 15), p3);
            float pr = (p0 + p1) + (p2r + p3);

            float s2 = pr * pr;                 // sum over lanes 0-15 via DPP row-shr
            DPPADDF(s2, 0x111)
            DPPADDF(s2, 0x112)
            DPPADDF(s2, 0x114)
            DPPADDF(s2, 0x118)                  // lane15 = full row sum
            float n2 = rlf(s2, 15);
            float invn = 1.0f / sqrtf(n2);
            vreg = pr * invn;                   // lane l holds v'[l], waves 0-3 consistent
            if (step == ns - 1 && t < 16) vf_out[t] = vreg;
        }
        // no barrier here: next L1 uses only own-wave registers; h1s writes are
        // separated from this step's readers by the barriers above.
    }
}

// -------------------- K3: scores = exp(dot(v_fin, emb_row_norm)); block sums -> atomic total --------------------
extern "C" __global__ __launch_bounds__(256)
void k_scores(const float* __restrict__ emb, const float* __restrict__ vf16,
              float* __restrict__ outP, double* __restrict__ totalp)
{
    __shared__ float vfs[16];
    const int tid = threadIdx.x;
    const int bid = blockIdx.x;
    const int q = tid & 3;
    if (tid < 16) vfs[tid] = vf16[tid];
    __syncthreads();
    float v0 = vfs[q * 4 + 0], v1 = vfs[q * 4 + 1], v2 = vfs[q * 4 + 2], v3 = vfs[q * 4 + 3];

    const float4* emb4 = (const float4*)emb;
    double bsum = 0.0;
    for (long long f = (long long)bid * 256 + tid; f < (long long)M_TOTAL * 4;
         f += (long long)K3_BLOCKS * 256) {
        float4 e = emb4[f];
        long long r = f >> 2;
        float sq = fmaf(e.x, e.x, fmaf(e.y, e.y, fmaf(e.z, e.z, e.w * e.w)));
        float d  = fmaf(e.x, v0, fmaf(e.y, v1, fmaf(e.z, v2, e.w * v3)));
        DPPADDF(sq, QP_XOR1)
        DPPADDF(d,  QP_XOR1)
        DPPADDF(sq, QP_XOR2)
        DPPADDF(d,  QP_XOR2)
        float ex = expf(d / sqrtf(sq));   // |score| <= 1, no overflow; softmax shift cancels
        if (q == 0) {
            outP[r] = ex;
            bsum += (double)ex;
        }
    }
#pragma unroll
    for (int off = 4; off <= 32; off <<= 1) bsum += __shfl_down(bsum, off);
    __shared__ double lred[4];
    if ((tid & 63) == 0) lred[tid >> 6] = bsum;
    __syncthreads();
    if (tid == 0) atomicAdd(totalp, lred[0] + lred[1] + lred[2] + lred[3]);
}

// -------------------- K5: normalize --------------------
extern "C" __global__ __launch_bounds__(256)
void k_scale(float* __restrict__ outP, const double* __restrict__ totalp)
{
    const float inv = 1.0f / (float)totalp[0];
    long long r4 = (long long)blockIdx.x * 256 + threadIdx.x;
    if (r4 < M_TOTAL / 4) {
        float4* p = (float4*)outP;
        float4 v = p[r4];
        v.x *= inv; v.y *= inv; v.z *= inv; v.w *= inv;
        p[r4] = v;
    }
}

extern "C" void kernel_launch(void* const* d_in, const int* in_sizes, int n_in,
                              void* d_out, int out_size, void* d_ws, size_t ws_size,
                              hipStream_t stream)
{
    const float* vsrc = (const float*)d_in[0];
    const float* vtgt = (const float*)d_in[1];
    const float* emb  = (const float*)d_in[2];
    const float* tc   = (const float*)d_in[3];
    // d_in[4] = bases: structure is hard-coded (omega[i][j] = -/+ coeffs[t*, k(i,j)])
    const float* w1 = (const float*)d_in[5];
    const float* b1 = (const float*)d_in[6];
    const float* w2 = (const float*)d_in[7];
    const float* b2 = (const float*)d_in[8];
    const float* w3 = (const float*)d_in[9];
    const float* b3 = (const float*)d_in[10];
    const float* gum = (const float*)d_in[11];
    const int* nsp   = (const int*)d_in[12];

    float* outP = (float*)d_out;          // pred_marking [2M]
    float* outL = outP + M_TOTAL;         // logits [64*512]

    double* wsd      = (double*)d_ws;
    double* partials = wsd;                         // 1024*32 doubles (region sized for 2048*32)
    double* totalp   = wsd + 2048 * 32;             // 1 double
    float*  vf       = (float*)(totalp + 1);        // 16 floats

    // Scratch tables live in the pred_marking output region; fully consumed by
    // k_steps before k_scores/k_scale overwrite outP.
    float* Rtab = outP;                   // 512*256 = 131072 floats
    float* w3R  = outP + 131072;          // 512*128 =  65536 floats
    float* w2R  = outP + 196608;          // 512*64  =  32768 floats

    // Fused front: reduce (1024 blocks) + expm (512) + weight relayout (516)
    k_front<<<K1_BLOCKS + 512 + 516, 256, 0, stream>>>(emb, vsrc, vtgt, partials,
                                                       tc, Rtab, w2, w3, w2R, w3R, totalp);
    k_steps<<<1, 512, 0, stream>>>(partials, w1, b1, b2, b3, w2R, w3R, Rtab, gum, nsp, outL, vf);
    k_scores<<<K3_BLOCKS, 256, 0, stream>>>(emb, vf, outP, totalp);
    k_scale<<<(M_TOTAL / 4 + 255) / 256, 256, 0, stream>>>(outP, totalp);
}